// Round 2
// baseline (845.750 us; speedup 1.0000x reference)
//
#include <hip/hip_runtime.h>
#include <hip/hip_bf16.h>

#define NUM_HEADS 16
#define DM 1024
#define DEPTH 64
#define BB 4
#define SS 1024
#define SL 1023            // S-1
#define M_ROWS (BB*SL)     // 4092

typedef __attribute__((ext_vector_type(8))) short short8;
typedef __attribute__((ext_vector_type(4))) float floatx4;

__device__ inline unsigned short f2bf(float f) {
  __hip_bfloat16 hb = __float2bfloat16(f);
  return *reinterpret_cast<unsigned short*>(&hb);
}
__device__ inline short8 ld_frag(const unsigned short* p) {
  return *reinterpret_cast<const short8*>(p);
}

// XOR granule swizzle: 16B granules within a 128B row; involution.
#define SWZ(row, g) (((g) ^ ((row) & 7)))

// async global->LDS, 16 B per lane (wave-uniform base + lane*16 dest)
#define GLDS(g, l) __builtin_amdgcn_global_load_lds( \
    (const __attribute__((address_space(1))) void*)(g), \
    (__attribute__((address_space(3))) void*)(l), 16, 0, 0)

// ---------------- prep kernels ----------------------------------------------
__global__ __launch_bounds__(256) void f32_to_bf16_vec(
    const float* __restrict__ in, unsigned short* __restrict__ out, int n8)
{
  int i = blockIdx.x * 256 + threadIdx.x;
  if (i >= n8) return;
  const float4 f0 = ((const float4*)in)[(size_t)i * 2];
  const float4 f1 = ((const float4*)in)[(size_t)i * 2 + 1];
  unsigned short t[8];
  t[0]=f2bf(f0.x); t[1]=f2bf(f0.y); t[2]=f2bf(f0.z); t[3]=f2bf(f0.w);
  t[4]=f2bf(f1.x); t[5]=f2bf(f1.y); t[6]=f2bf(f1.z); t[7]=f2bf(f1.w);
  ((uint4*)out)[i] = *(uint4*)t;
}

// W[1024][1024] fp32 -> WT[1024][1024] bf16 with WT[n][k] = W[k][n]
__global__ __launch_bounds__(256) void transpose_to_bf16(
    const float* __restrict__ W, unsigned short* __restrict__ WT)
{
  __shared__ unsigned short tile[64][72];
  const int tid = threadIdx.x;
  const int k0 = blockIdx.y * 64, n0 = blockIdx.x * 64;
  {
    const int kl = tid >> 2, nc = (tid & 3) * 16;
    const float* src = W + (size_t)(k0 + kl) * DM + n0 + nc;
    #pragma unroll
    for (int j = 0; j < 16; j += 4) {
      float4 f = *(const float4*)(src + j);
      tile[nc + j + 0][kl] = f2bf(f.x);
      tile[nc + j + 1][kl] = f2bf(f.y);
      tile[nc + j + 2][kl] = f2bf(f.z);
      tile[nc + j + 3][kl] = f2bf(f.w);
    }
  }
  __syncthreads();
  {
    const int nl = tid >> 2, kc = (tid & 3) * 16;
    unsigned short tmp[16];
    #pragma unroll
    for (int j = 0; j < 16; j++) tmp[j] = tile[nl][kc + j];
    unsigned short* dst = WT + (size_t)(n0 + nl) * DM + k0 + kc;
    *(uint4*)&dst[0] = *(uint4*)&tmp[0];
    *(uint4*)&dst[8] = *(uint4*)&tmp[8];
  }
}

// ---------------- GEMM: C[M x 1024] = A * BT^T + bias -----------------------
// A bf16 [M][K], BT bf16 [N][K]. BM=64 BN=128 BK=64, 4 waves (2x2), wave 32x64,
// 16 MFMA / K-step / wave. global_load_lds (width 16) double-buffered,
// conflict-free XOR-swizzled LDS (linear dest + inverse-swizzled source).
template <bool OUT_BF16>
__global__ __launch_bounds__(256) void gemm_bt(
    const unsigned short* __restrict__ A,   // [M][DM] bf16
    const unsigned short* __restrict__ BT,  // [DM][DM] bf16 (n-major)
    const float* __restrict__ bias,
    void* __restrict__ Cv, int M)
{
  constexpr int BM = 64, BN = 128, BK = 64;
  __shared__ __align__(16) unsigned short As[2][BM * BK];   // 8 KB / buf
  __shared__ __align__(16) unsigned short Bs[2][BN * BK];   // 16 KB / buf

  const int tid = threadIdx.x;
  const int w = tid >> 6, lane = tid & 63, q4 = lane >> 4, l16 = lane & 15;
  const int wm = w >> 1, wn = w & 1;
  const int rb = blockIdx.y * BM;
  const int cb = blockIdx.x * BN;

  // staging: each 4KB chunk = 32 rows x 128B; thread t -> row t>>3, phys granule t&7
  const int srow = tid >> 3;                   // 0..31
  const int lg   = (tid & 7) ^ (srow & 7);     // logical granule (inverse swizzle)
  int ar0 = rb + srow;       if (ar0 >= M) ar0 = M - 1;
  int ar1 = rb + 32 + srow;  if (ar1 >= M) ar1 = M - 1;
  const unsigned short* a_src0 = A + (size_t)ar0 * DM + lg * 8;
  const unsigned short* a_src1 = A + (size_t)ar1 * DM + lg * 8;
  const unsigned short* b_src0 = BT + (size_t)(cb      + srow) * DM + lg * 8;
  const unsigned short* b_src1 = BT + (size_t)(cb + 32 + srow) * DM + lg * 8;
  const unsigned short* b_src2 = BT + (size_t)(cb + 64 + srow) * DM + lg * 8;
  const unsigned short* b_src3 = BT + (size_t)(cb + 96 + srow) * DM + lg * 8;

  // fragment read offsets (u16 index), swizzled
  int aoff[2][2], boff[4][2];
  #pragma unroll
  for (int i = 0; i < 2; i++)
    #pragma unroll
    for (int hf = 0; hf < 2; hf++) {
      int r = wm * 32 + i * 16 + l16;
      aoff[i][hf] = r * BK + SWZ(r, q4 + 4 * hf) * 8;
    }
  #pragma unroll
  for (int j = 0; j < 4; j++)
    #pragma unroll
    for (int hf = 0; hf < 2; hf++) {
      int r = wn * 64 + j * 16 + l16;
      boff[j][hf] = r * BK + SWZ(r, q4 + 4 * hf) * 8;
    }

  floatx4 acc[2][4];
  #pragma unroll
  for (int i = 0; i < 2; i++)
    #pragma unroll
    for (int j = 0; j < 4; j++) acc[i][j] = (floatx4){0.f,0.f,0.f,0.f};

  // prologue: stage tile 0
  GLDS(a_src0, &As[0][tid * 8]);
  GLDS(a_src1, &As[0][2048 + tid * 8]);
  GLDS(b_src0, &Bs[0][tid * 8]);
  GLDS(b_src1, &Bs[0][2048 + tid * 8]);
  GLDS(b_src2, &Bs[0][4096 + tid * 8]);
  GLDS(b_src3, &Bs[0][6144 + tid * 8]);
  __syncthreads();

  int cur = 0;
  constexpr int NT = DM / BK;   // 16
  for (int t = 0; t < NT; ++t) {
    if (t + 1 < NT) {
      const int kn = (t + 1) * BK;
      GLDS(a_src0 + kn, &As[cur ^ 1][tid * 8]);
      GLDS(a_src1 + kn, &As[cur ^ 1][2048 + tid * 8]);
      GLDS(b_src0 + kn, &Bs[cur ^ 1][tid * 8]);
      GLDS(b_src1 + kn, &Bs[cur ^ 1][2048 + tid * 8]);
      GLDS(b_src2 + kn, &Bs[cur ^ 1][4096 + tid * 8]);
      GLDS(b_src3 + kn, &Bs[cur ^ 1][6144 + tid * 8]);
    }
    #pragma unroll
    for (int hf = 0; hf < 2; hf++) {
      short8 af0 = ld_frag(&As[cur][aoff[0][hf]]);
      short8 af1 = ld_frag(&As[cur][aoff[1][hf]]);
      short8 bf0 = ld_frag(&Bs[cur][boff[0][hf]]);
      short8 bf1 = ld_frag(&Bs[cur][boff[1][hf]]);
      short8 bf2 = ld_frag(&Bs[cur][boff[2][hf]]);
      short8 bf3 = ld_frag(&Bs[cur][boff[3][hf]]);
      acc[0][0] = __builtin_amdgcn_mfma_f32_16x16x32_bf16(af0, bf0, acc[0][0], 0,0,0);
      acc[0][1] = __builtin_amdgcn_mfma_f32_16x16x32_bf16(af0, bf1, acc[0][1], 0,0,0);
      acc[0][2] = __builtin_amdgcn_mfma_f32_16x16x32_bf16(af0, bf2, acc[0][2], 0,0,0);
      acc[0][3] = __builtin_amdgcn_mfma_f32_16x16x32_bf16(af0, bf3, acc[0][3], 0,0,0);
      acc[1][0] = __builtin_amdgcn_mfma_f32_16x16x32_bf16(af1, bf0, acc[1][0], 0,0,0);
      acc[1][1] = __builtin_amdgcn_mfma_f32_16x16x32_bf16(af1, bf1, acc[1][1], 0,0,0);
      acc[1][2] = __builtin_amdgcn_mfma_f32_16x16x32_bf16(af1, bf2, acc[1][2], 0,0,0);
      acc[1][3] = __builtin_amdgcn_mfma_f32_16x16x32_bf16(af1, bf3, acc[1][3], 0,0,0);
    }
    __syncthreads();
    cur ^= 1;
  }

  // epilogue
  #pragma unroll
  for (int j = 0; j < 4; j++) {
    int col = cb + wn * 64 + j * 16 + l16;
    float bb = bias[col];
    #pragma unroll
    for (int i = 0; i < 2; i++) {
      #pragma unroll
      for (int r = 0; r < 4; r++) {
        int m = rb + wm * 32 + i * 16 + q4 * 4 + r;
        if (m < M) {
          float val = acc[i][j][r] + bb;
          if (OUT_BF16) ((unsigned short*)Cv)[(size_t)m * DM + col] = f2bf(val);
          else __builtin_nontemporal_store(val, &((float*)Cv)[(size_t)m * DM + col]);
        }
      }
    }
  }
}

// ---------------- Attention --------------------------------------------------
// grid (16 q-tiles, 16 heads, 4 batch); block 256 = 4 waves, wave owns 16 q rows.
// v2: double-buffered K (pass1: 1 barrier/iter), T14-split V staging,
// XOR-swizzled conflict-free [64][64] LDS, hoisted Q frags, nontemporal Att.
__global__ __launch_bounds__(256) void attn_kernel(
    const float* __restrict__ Q, const float* __restrict__ Kg,
    const float* __restrict__ Mask, const unsigned short* __restrict__ VV,
    float* __restrict__ Att, unsigned short* __restrict__ Out2)
{
  const int qt = blockIdx.x, h = blockIdx.y, b = blockIdx.z;
  const int tid = threadIdx.x;
  const int w = tid >> 6, lane = tid & 63, q4 = lane >> 4, l16 = lane & 15;
  const int qi0 = qt * 64;
  const int qb = w * 16;

  __shared__ __align__(16) unsigned short qsh[64][64];      // 8 KB
  __shared__ __align__(16) unsigned short ksh[2][64][64];   // 16 KB (dbuf)
  __shared__ __align__(16) unsigned short vshT[64][64];     // 8 KB  [d][key]
  __shared__ __align__(16) unsigned short psh[4][16][64];   // 8 KB  per-wave P
  // total 40960 B -> 4 blocks/CU

  // ---- stage Q (swizzled) ----
  {
    const int qr = tid >> 2, c = tid & 3;
    const int qi = qi0 + qr;
    unsigned short t0[8], t1[8];
    if (qi < SL) {
      const float* src = Q + ((size_t)b * SS + qi + 1) * DM + h * DEPTH + c * 16;
      float4 f0 = ((const float4*)src)[0], f1 = ((const float4*)src)[1];
      float4 f2 = ((const float4*)src)[2], f3 = ((const float4*)src)[3];
      t0[0]=f2bf(f0.x); t0[1]=f2bf(f0.y); t0[2]=f2bf(f0.z); t0[3]=f2bf(f0.w);
      t0[4]=f2bf(f1.x); t0[5]=f2bf(f1.y); t0[6]=f2bf(f1.z); t0[7]=f2bf(f1.w);
      t1[0]=f2bf(f2.x); t1[1]=f2bf(f2.y); t1[2]=f2bf(f2.z); t1[3]=f2bf(f2.w);
      t1[4]=f2bf(f3.x); t1[5]=f2bf(f3.y); t1[6]=f2bf(f3.z); t1[7]=f2bf(f3.w);
    } else {
      #pragma unroll
      for (int j = 0; j < 8; j++) { t0[j] = 0; t1[j] = 0; }
    }
    *(uint4*)&qsh[qr][SWZ(qr, 2*c)     * 8] = *(uint4*)t0;
    *(uint4*)&qsh[qr][SWZ(qr, 2*c + 1) * 8] = *(uint4*)t1;
  }

  const int kr = tid >> 2, kc = tid & 3;        // K staging coords
  auto loadK = [&](int kt, float4* f) {
    const int kj = kt * 64 + kr;
    if (kj < SL) {
      const float* src = Kg + ((size_t)b * SS + kj) * DM + h * DEPTH + kc * 16;
      f[0] = ((const float4*)src)[0]; f[1] = ((const float4*)src)[1];
      f[2] = ((const float4*)src)[2]; f[3] = ((const float4*)src)[3];
    } else {
      f[0] = f[1] = f[2] = f[3] = (float4){0.f,0.f,0.f,0.f};
    }
  };
  auto writeK = [&](int buf, const float4* f) {
    unsigned short t0[8], t1[8];
    t0[0]=f2bf(f[0].x); t0[1]=f2bf(f[0].y); t0[2]=f2bf(f[0].z); t0[3]=f2bf(f[0].w);
    t0[4]=f2bf(f[1].x); t0[5]=f2bf(f[1].y); t0[6]=f2bf(f[1].z); t0[7]=f2bf(f[1].w);
    t1[0]=f2bf(f[2].x); t1[1]=f2bf(f[2].y); t1[2]=f2bf(f[2].z); t1[3]=f2bf(f[2].w);
    t1[4]=f2bf(f[3].x); t1[5]=f2bf(f[3].y); t1[6]=f2bf(f[3].z); t1[7]=f2bf(f[3].w);
    *(uint4*)&ksh[buf][kr][SWZ(kr, 2*kc)     * 8] = *(uint4*)t0;
    *(uint4*)&ksh[buf][kr][SWZ(kr, 2*kc + 1) * 8] = *(uint4*)t1;
  };
  const int vd = tid & 63, vg = (tid >> 6) * 2;   // V coords (cols vg*8 .. vg*8+15)
  auto loadV = [&](int kt, unsigned short* t) {
    #pragma unroll
    for (int j = 0; j < 16; j++) {
      int kj = kt * 64 + vg * 8 + j;
      t[j] = (kj < SL) ? VV[((size_t)b * SL + kj) * DM + h * DEPTH + vd] : (unsigned short)0;
    }
  };
  auto writeV = [&](const unsigned short* t) {
    *(uint4*)&vshT[vd][SWZ(vd, vg)     * 8] = *(uint4*)&t[0];
    *(uint4*)&vshT[vd][SWZ(vd, vg + 1) * 8] = *(uint4*)&t[8];
  };

  float4 kreg[4];
  loadK(0, kreg);
  writeK(0, kreg);
  __syncthreads();

  // hoisted Q fragments (loop-invariant)
  const int qrow = qb + l16;
  const short8 qf0 = ld_frag(&qsh[qrow][SWZ(qrow, q4)     * 8]);
  const short8 qf1 = ld_frag(&qsh[qrow][SWZ(qrow, 4 + q4) * 8]);
  const int qi_b = qi0 + qb + q4 * 4;

  // ---- pass 1: rowsums (1 barrier/iter, K double-buffered) ----
  float rsv[4] = {0.f, 0.f, 0.f, 0.f};
  for (int kt = 0; kt < 16; kt++) {
    const int cur = kt & 1;
    if (kt < 15) loadK(kt + 1, kreg);
    #pragma unroll
    for (int nt = 0; nt < 4; nt++) {
      const int krow = nt * 16 + l16;
      floatx4 s = (floatx4){0.f,0.f,0.f,0.f};
      s = __builtin_amdgcn_mfma_f32_16x16x32_bf16(
            qf0, ld_frag(&ksh[cur][krow][SWZ(krow, q4)     * 8]), s, 0,0,0);
      s = __builtin_amdgcn_mfma_f32_16x16x32_bf16(
            qf1, ld_frag(&ksh[cur][krow][SWZ(krow, 4 + q4) * 8]), s, 0,0,0);
      int kj = kt * 64 + nt * 16 + l16;
      bool kv = kj < SL;
      const float* mp = Mask + ((size_t)b * SL + qi_b) * SL + kj;
      #pragma unroll
      for (int r = 0; r < 4; r++) {
        int qi = qi_b + r;
        float mval = (kv && qi < SL) ? mp[(size_t)r * SL] : 0.f;
        float sv = fmaxf(s[r] * 0.125f, 0.f) + mval * (-1e9f);
        rsv[r] += kv ? __expf(sv) : 0.f;
      }
    }
    if (kt < 15) writeK(cur ^ 1, kreg);
    __syncthreads();
  }
  #pragma unroll
  for (int r = 0; r < 4; r++) {
    #pragma unroll
    for (int off = 1; off < 16; off <<= 1) rsv[r] += __shfl_xor(rsv[r], off, 64);
  }
  float inv[4];
  #pragma unroll
  for (int r = 0; r < 4; r++) inv[r] = 1.f / rsv[r];

  // ---- pass 2: att + PV ----
  floatx4 oacc[4];
  #pragma unroll
  for (int i = 0; i < 4; i++) oacc[i] = (floatx4){0.f,0.f,0.f,0.f};

  loadK(0, kreg);
  writeK(0, kreg);
  __syncthreads();

  for (int kt = 0; kt < 16; kt++) {
    const int cur = kt & 1;
    unsigned short vreg[16];
    loadV(kt, vreg);                     // issue V loads early (T14 split)
    if (kt < 15) loadK(kt + 1, kreg);    // issue next-K loads early
    #pragma unroll
    for (int nt = 0; nt < 4; nt++) {
      const int krow = nt * 16 + l16;
      floatx4 s = (floatx4){0.f,0.f,0.f,0.f};
      s = __builtin_amdgcn_mfma_f32_16x16x32_bf16(
            qf0, ld_frag(&ksh[cur][krow][SWZ(krow, q4)     * 8]), s, 0,0,0);
      s = __builtin_amdgcn_mfma_f32_16x16x32_bf16(
            qf1, ld_frag(&ksh[cur][krow][SWZ(krow, 4 + q4) * 8]), s, 0,0,0);
      int kj = kt * 64 + nt * 16 + l16;
      bool kv = kj < SL;
      const float* mp = Mask + ((size_t)b * SL + qi_b) * SL + kj;
      const int pg = nt * 2 + (l16 >> 3), pc = l16 & 7;
      #pragma unroll
      for (int r = 0; r < 4; r++) {
        int qi = qi_b + r;
        bool qv = qi < SL;
        float mval = (kv && qv) ? mp[(size_t)r * SL] : 0.f;
        float sv = fmaxf(s[r] * 0.125f, 0.f) + mval * (-1e9f);
        float p = kv ? __expf(sv) : 0.f;
        float pn = p * inv[r];
        if (kv && qv)
          __builtin_nontemporal_store(pn,
              &Att[(((size_t)(b * NUM_HEADS + h)) * SL + qi) * SL + kj]);
        const int prow = q4 * 4 + r;
        psh[w][prow][SWZ(prow, pg) * 8 + pc] = f2bf(pn);
      }
    }
    writeV(vreg);                        // V landed during QK phase
    if (kt < 15) writeK(cur ^ 1, kreg);
    short8 pa0 = ld_frag(&psh[w][l16][SWZ(l16, q4)     * 8]);  // own-wave P
    short8 pa1 = ld_frag(&psh[w][l16][SWZ(l16, 4 + q4) * 8]);
    __syncthreads();                     // vshT + next-K ready
    #pragma unroll
    for (int nt2 = 0; nt2 < 4; nt2++) {
      const int vrow = nt2 * 16 + l16;
      oacc[nt2] = __builtin_amdgcn_mfma_f32_16x16x32_bf16(
                    pa0, ld_frag(&vshT[vrow][SWZ(vrow, q4)     * 8]), oacc[nt2], 0,0,0);
      oacc[nt2] = __builtin_amdgcn_mfma_f32_16x16x32_bf16(
                    pa1, ld_frag(&vshT[vrow][SWZ(vrow, 4 + q4) * 8]), oacc[nt2], 0,0,0);
    }
    __syncthreads();                     // all waves done with vshT before next writeV
  }

  #pragma unroll
  for (int nt2 = 0; nt2 < 4; nt2++) {
    #pragma unroll
    for (int r = 0; r < 4; r++) {
      int qi = qi0 + qb + q4 * 4 + r;
      if (qi < SL)
        Out2[((size_t)b * SL + qi) * DM + h * DEPTH + nt2 * 16 + l16] = f2bf(oacc[nt2][r]);
    }
  }
}

extern "C" void kernel_launch(void* const* d_in, const int* in_sizes, int n_in,
                              void* d_out, int out_size, void* d_ws, size_t ws_size,
                              hipStream_t stream) {
  const float* v    = (const float*)d_in[0];
  const float* k    = (const float*)d_in[1];
  const float* q    = (const float*)d_in[2];
  const float* mask = (const float*)d_in[3];
  const float* Wv   = (const float*)d_in[4];
  const float* bv   = (const float*)d_in[5];
  const float* Wd   = (const float*)d_in[6];
  const float* bd   = (const float*)d_in[7];

  float* out = (float*)d_out;                                  // (4,1023,1024) fp32
  float* att = out + (size_t)M_ROWS * DM;                      // (4,16,1023,1023) fp32
  unsigned short* vv   = (unsigned short*)d_ws;                // bf16 (4,1023,1024)
  unsigned short* out2 = vv + (size_t)M_ROWS * DM;             // bf16 (4,1023,1024)

  // scratch inside the att region (dead until attn_kernel writes it):
  unsigned short* WvT = (unsigned short*)att;                  // bf16 [1024][1024] (n-major)
  unsigned short* vbf = WvT + (size_t)DM * DM;                 // bf16 (4,1023,1024)
  // after attn, vv is dead -> reuse its region for WdT:
  unsigned short* WdT = vv;                                    // bf16 [1024][1024]

  const int n8 = (M_ROWS * DM) / 8;                            // 523776

  f32_to_bf16_vec<<<dim3((n8 + 255) / 256), 256, 0, stream>>>(v, vbf, n8);
  transpose_to_bf16<<<dim3(16, 16), 256, 0, stream>>>(Wv, WvT);
  gemm_bt<true><<<dim3(DM/128, (M_ROWS+63)/64), 256, 0, stream>>>(vbf, WvT, bv, (void*)vv, M_ROWS);
  attn_kernel<<<dim3(16, NUM_HEADS, BB), 256, 0, stream>>>(q, k, mask, vv, att, out2);
  transpose_to_bf16<<<dim3(16, 16), 256, 0, stream>>>(Wd, WdT);
  gemm_bt<false><<<dim3(DM/128, (M_ROWS+63)/64), 256, 0, stream>>>(out2, WdT, bd, (void*)out, M_ROWS);
}

// Round 3
// 843.946 us; speedup vs baseline: 1.0021x; 1.0021x over previous
//
#include <hip/hip_runtime.h>
#include <hip/hip_bf16.h>

#define NUM_HEADS 16
#define DM 1024
#define DEPTH 64
#define BB 4
#define SS 1024
#define SL 1023            // S-1
#define M_ROWS (BB*SL)     // 4092

typedef __attribute__((ext_vector_type(8))) short short8;
typedef __attribute__((ext_vector_type(4))) float floatx4;

__device__ inline unsigned short f2bf(float f) {
  __hip_bfloat16 hb = __float2bfloat16(f);
  return *reinterpret_cast<unsigned short*>(&hb);
}
__device__ inline short8 ld_frag(const unsigned short* p) {
  return *reinterpret_cast<const short8*>(p);
}

// XOR granule swizzle: 16B granules within a 128B row; involution.
#define SWZ(row, g) (((g) ^ ((row) & 7)))

// async global->LDS, 16 B per lane. LDS base MUST be wave-uniform (SGPR) —
// a divergent pointer makes the compiler waterfall 64 serialized issues.
#define GLDS(g, l) __builtin_amdgcn_global_load_lds( \
    (const __attribute__((address_space(1))) void*)(g), \
    (__attribute__((address_space(3))) void*)(l), 16, 0, 0)

// ---------------- prep kernels ----------------------------------------------
__global__ __launch_bounds__(256) void f32_to_bf16_vec(
    const float* __restrict__ in, unsigned short* __restrict__ out, int n8)
{
  int i = blockIdx.x * 256 + threadIdx.x;
  if (i >= n8) return;
  const float4 f0 = ((const float4*)in)[(size_t)i * 2];
  const float4 f1 = ((const float4*)in)[(size_t)i * 2 + 1];
  unsigned short t[8];
  t[0]=f2bf(f0.x); t[1]=f2bf(f0.y); t[2]=f2bf(f0.z); t[3]=f2bf(f0.w);
  t[4]=f2bf(f1.x); t[5]=f2bf(f1.y); t[6]=f2bf(f1.z); t[7]=f2bf(f1.w);
  ((uint4*)out)[i] = *(uint4*)t;
}

// W[1024][1024] fp32 -> WT[1024][1024] bf16 with WT[n][k] = W[k][n]
__global__ __launch_bounds__(256) void transpose_to_bf16(
    const float* __restrict__ W, unsigned short* __restrict__ WT)
{
  __shared__ unsigned short tile[64][72];
  const int tid = threadIdx.x;
  const int k0 = blockIdx.y * 64, n0 = blockIdx.x * 64;
  {
    const int kl = tid >> 2, nc = (tid & 3) * 16;
    const float* src = W + (size_t)(k0 + kl) * DM + n0 + nc;
    #pragma unroll
    for (int j = 0; j < 16; j += 4) {
      float4 f = *(const float4*)(src + j);
      tile[nc + j + 0][kl] = f2bf(f.x);
      tile[nc + j + 1][kl] = f2bf(f.y);
      tile[nc + j + 2][kl] = f2bf(f.z);
      tile[nc + j + 3][kl] = f2bf(f.w);
    }
  }
  __syncthreads();
  {
    const int nl = tid >> 2, kc = (tid & 3) * 16;
    unsigned short tmp[16];
    #pragma unroll
    for (int j = 0; j < 16; j++) tmp[j] = tile[nl][kc + j];
    unsigned short* dst = WT + (size_t)(n0 + nl) * DM + k0 + kc;
    *(uint4*)&dst[0] = *(uint4*)&tmp[0];
    *(uint4*)&dst[8] = *(uint4*)&tmp[8];
  }
}

// ---------------- GEMM: C[M x 1024] = A * BT^T + bias -----------------------
// A bf16 [M][K], BT bf16 [N][K]. BM=64 BN=128 BK=64, 4 waves (2x2), wave 32x64,
// 16 MFMA / K-step / wave. global_load_lds width-16, double-buffered LDS,
// conflict-free XOR-swizzled (linear LDS dest + inverse-swizzled source).
// LDS dest base is readfirstlane'd (SGPR) — wave-uniform, no waterfall.
template <bool OUT_BF16>
__global__ __launch_bounds__(256) void gemm_bt(
    const unsigned short* __restrict__ A,   // [M][DM] bf16
    const unsigned short* __restrict__ BT,  // [DM][DM] bf16 (n-major)
    const float* __restrict__ bias,
    void* __restrict__ Cv, int M)
{
  constexpr int BM = 64, BN = 128, BK = 64;
  __shared__ __align__(16) unsigned short As[2][BM * BK];   // 8 KB / buf
  __shared__ __align__(16) unsigned short Bs[2][BN * BK];   // 16 KB / buf

  const int tid = threadIdx.x;
  const int w = tid >> 6, lane = tid & 63, q4 = lane >> 4, l16 = lane & 15;
  const int wm = w >> 1, wn = w & 1;
  const int rb = blockIdx.y * BM;
  const int cb = blockIdx.x * BN;

  // wave-uniform LDS offset (u16 index): wave w covers bytes [w*1024, w*1024+1024)
  const int wbase = __builtin_amdgcn_readfirstlane(w * 512);

  // staging: each 4KB chunk = 32 rows x 128B; thread t -> row t>>3, phys granule t&7
  const int srow = tid >> 3;                   // 0..31
  const int lg   = (tid & 7) ^ (srow & 7);     // logical granule (inverse swizzle)
  int ar0 = rb + srow;       if (ar0 >= M) ar0 = M - 1;
  int ar1 = rb + 32 + srow;  if (ar1 >= M) ar1 = M - 1;
  const unsigned short* a_src0 = A + (size_t)ar0 * DM + lg * 8;
  const unsigned short* a_src1 = A + (size_t)ar1 * DM + lg * 8;
  const unsigned short* b_src0 = BT + (size_t)(cb      + srow) * DM + lg * 8;
  const unsigned short* b_src1 = BT + (size_t)(cb + 32 + srow) * DM + lg * 8;
  const unsigned short* b_src2 = BT + (size_t)(cb + 64 + srow) * DM + lg * 8;
  const unsigned short* b_src3 = BT + (size_t)(cb + 96 + srow) * DM + lg * 8;

  // fragment read offsets (u16 index), swizzled
  int aoff[2][2], boff[4][2];
  #pragma unroll
  for (int i = 0; i < 2; i++)
    #pragma unroll
    for (int hf = 0; hf < 2; hf++) {
      int r = wm * 32 + i * 16 + l16;
      aoff[i][hf] = r * BK + SWZ(r, q4 + 4 * hf) * 8;
    }
  #pragma unroll
  for (int j = 0; j < 4; j++)
    #pragma unroll
    for (int hf = 0; hf < 2; hf++) {
      int r = wn * 64 + j * 16 + l16;
      boff[j][hf] = r * BK + SWZ(r, q4 + 4 * hf) * 8;
    }

  floatx4 acc[2][4];
  #pragma unroll
  for (int i = 0; i < 2; i++)
    #pragma unroll
    for (int j = 0; j < 4; j++) acc[i][j] = (floatx4){0.f,0.f,0.f,0.f};

  // prologue: stage tile 0
  GLDS(a_src0, &As[0][wbase]);
  GLDS(a_src1, &As[0][2048 + wbase]);
  GLDS(b_src0, &Bs[0][wbase]);
  GLDS(b_src1, &Bs[0][2048 + wbase]);
  GLDS(b_src2, &Bs[0][4096 + wbase]);
  GLDS(b_src3, &Bs[0][6144 + wbase]);
  __syncthreads();

  int cur = 0;
  constexpr int NT = DM / BK;   // 16
  for (int t = 0; t < NT; ++t) {
    if (t + 1 < NT) {
      const int kn = (t + 1) * BK;
      GLDS(a_src0 + kn, &As[cur ^ 1][wbase]);
      GLDS(a_src1 + kn, &As[cur ^ 1][2048 + wbase]);
      GLDS(b_src0 + kn, &Bs[cur ^ 1][wbase]);
      GLDS(b_src1 + kn, &Bs[cur ^ 1][2048 + wbase]);
      GLDS(b_src2 + kn, &Bs[cur ^ 1][4096 + wbase]);
      GLDS(b_src3 + kn, &Bs[cur ^ 1][6144 + wbase]);
    }
    #pragma unroll
    for (int hf = 0; hf < 2; hf++) {
      short8 af0 = ld_frag(&As[cur][aoff[0][hf]]);
      short8 af1 = ld_frag(&As[cur][aoff[1][hf]]);
      short8 bf0 = ld_frag(&Bs[cur][boff[0][hf]]);
      short8 bf1 = ld_frag(&Bs[cur][boff[1][hf]]);
      short8 bf2 = ld_frag(&Bs[cur][boff[2][hf]]);
      short8 bf3 = ld_frag(&Bs[cur][boff[3][hf]]);
      acc[0][0] = __builtin_amdgcn_mfma_f32_16x16x32_bf16(af0, bf0, acc[0][0], 0,0,0);
      acc[0][1] = __builtin_amdgcn_mfma_f32_16x16x32_bf16(af0, bf1, acc[0][1], 0,0,0);
      acc[0][2] = __builtin_amdgcn_mfma_f32_16x16x32_bf16(af0, bf2, acc[0][2], 0,0,0);
      acc[0][3] = __builtin_amdgcn_mfma_f32_16x16x32_bf16(af0, bf3, acc[0][3], 0,0,0);
      acc[1][0] = __builtin_amdgcn_mfma_f32_16x16x32_bf16(af1, bf0, acc[1][0], 0,0,0);
      acc[1][1] = __builtin_amdgcn_mfma_f32_16x16x32_bf16(af1, bf1, acc[1][1], 0,0,0);
      acc[1][2] = __builtin_amdgcn_mfma_f32_16x16x32_bf16(af1, bf2, acc[1][2], 0,0,0);
      acc[1][3] = __builtin_amdgcn_mfma_f32_16x16x32_bf16(af1, bf3, acc[1][3], 0,0,0);
    }
    __syncthreads();
    cur ^= 1;
  }

  // epilogue
  #pragma unroll
  for (int j = 0; j < 4; j++) {
    int col = cb + wn * 64 + j * 16 + l16;
    float bb = bias[col];
    #pragma unroll
    for (int i = 0; i < 2; i++) {
      #pragma unroll
      for (int r = 0; r < 4; r++) {
        int m = rb + wm * 32 + i * 16 + q4 * 4 + r;
        if (m < M) {
          float val = acc[i][j][r] + bb;
          if (OUT_BF16) ((unsigned short*)Cv)[(size_t)m * DM + col] = f2bf(val);
          else __builtin_nontemporal_store(val, &((float*)Cv)[(size_t)m * DM + col]);
        }
      }
    }
  }
}

// ---------------- Attention --------------------------------------------------
// grid (16 q-tiles, 16 heads, 4 batch); block 256 = 4 waves, wave owns 16 q rows.
// v3: LDS = 24 KB (6 blocks/CU). qsh is reused as psh after Q-frag hoist.
// Pass 1: K double-buffered across ksh2[0/1], 1 barrier/iter.
// Pass 2: K=ksh2[0], V^T=ksh2[1] single-buffered, reg-staged early-issue loads.
__global__ __launch_bounds__(256) void attn_kernel(
    const float* __restrict__ Q, const float* __restrict__ Kg,
    const float* __restrict__ Mask, const unsigned short* __restrict__ VV,
    float* __restrict__ Att, unsigned short* __restrict__ Out2)
{
  const int qt = blockIdx.x, h = blockIdx.y, b = blockIdx.z;
  const int tid = threadIdx.x;
  const int w = tid >> 6, lane = tid & 63, q4 = lane >> 4, l16 = lane & 15;
  const int qi0 = qt * 64;
  const int qb = w * 16;

  __shared__ __align__(16) unsigned short qsh[64][64];       // 8 KB, reused as psh
  __shared__ __align__(16) unsigned short ksh2[2][64][64];   // 16 KB
  // per-wave P region inside qsh (Q is hoisted to regs before first P write)
  unsigned short (*psh)[64] = &qsh[w * 16];

  // ---- stage Q (swizzled) ----
  {
    const int qr = tid >> 2, c = tid & 3;
    const int qi = qi0 + qr;
    unsigned short t0[8], t1[8];
    if (qi < SL) {
      const float* src = Q + ((size_t)b * SS + qi + 1) * DM + h * DEPTH + c * 16;
      float4 f0 = ((const float4*)src)[0], f1 = ((const float4*)src)[1];
      float4 f2 = ((const float4*)src)[2], f3 = ((const float4*)src)[3];
      t0[0]=f2bf(f0.x); t0[1]=f2bf(f0.y); t0[2]=f2bf(f0.z); t0[3]=f2bf(f0.w);
      t0[4]=f2bf(f1.x); t0[5]=f2bf(f1.y); t0[6]=f2bf(f1.z); t0[7]=f2bf(f1.w);
      t1[0]=f2bf(f2.x); t1[1]=f2bf(f2.y); t1[2]=f2bf(f2.z); t1[3]=f2bf(f2.w);
      t1[4]=f2bf(f3.x); t1[5]=f2bf(f3.y); t1[6]=f2bf(f3.z); t1[7]=f2bf(f3.w);
    } else {
      #pragma unroll
      for (int j = 0; j < 8; j++) { t0[j] = 0; t1[j] = 0; }
    }
    *(uint4*)&qsh[qr][SWZ(qr, 2*c)     * 8] = *(uint4*)t0;
    *(uint4*)&qsh[qr][SWZ(qr, 2*c + 1) * 8] = *(uint4*)t1;
  }

  const int kr = tid >> 2, kc = tid & 3;        // K staging coords
  auto loadK = [&](int kt, float4* f) {
    const int kj = kt * 64 + kr;
    if (kj < SL) {
      const float* src = Kg + ((size_t)b * SS + kj) * DM + h * DEPTH + kc * 16;
      f[0] = ((const float4*)src)[0]; f[1] = ((const float4*)src)[1];
      f[2] = ((const float4*)src)[2]; f[3] = ((const float4*)src)[3];
    } else {
      f[0] = f[1] = f[2] = f[3] = (float4){0.f,0.f,0.f,0.f};
    }
  };
  auto writeK = [&](int buf, const float4* f) {
    unsigned short t0[8], t1[8];
    t0[0]=f2bf(f[0].x); t0[1]=f2bf(f[0].y); t0[2]=f2bf(f[0].z); t0[3]=f2bf(f[0].w);
    t0[4]=f2bf(f[1].x); t0[5]=f2bf(f[1].y); t0[6]=f2bf(f[1].z); t0[7]=f2bf(f[1].w);
    t1[0]=f2bf(f[2].x); t1[1]=f2bf(f[2].y); t1[2]=f2bf(f[2].z); t1[3]=f2bf(f[2].w);
    t1[4]=f2bf(f[3].x); t1[5]=f2bf(f[3].y); t1[6]=f2bf(f[3].z); t1[7]=f2bf(f[3].w);
    *(uint4*)&ksh2[buf][kr][SWZ(kr, 2*kc)     * 8] = *(uint4*)t0;
    *(uint4*)&ksh2[buf][kr][SWZ(kr, 2*kc + 1) * 8] = *(uint4*)t1;
  };
  const int vd = tid & 63, vg = (tid >> 6) * 2;   // V^T coords (cols vg*8 .. vg*8+15)
  auto loadV = [&](int kt, unsigned short* t) {
    #pragma unroll
    for (int j = 0; j < 16; j++) {
      int kj = kt * 64 + vg * 8 + j;
      t[j] = (kj < SL) ? VV[((size_t)b * SL + kj) * DM + h * DEPTH + vd] : (unsigned short)0;
    }
  };
  auto writeV = [&](const unsigned short* t) {    // into ksh2[1]
    *(uint4*)&ksh2[1][vd][SWZ(vd, vg)     * 8] = *(uint4*)&t[0];
    *(uint4*)&ksh2[1][vd][SWZ(vd, vg + 1) * 8] = *(uint4*)&t[8];
  };

  float4 kreg[4];
  loadK(0, kreg);
  writeK(0, kreg);
  __syncthreads();

  // hoisted Q fragments (qsh is dead for Q after this; reused as psh in pass 2)
  const int qrow = qb + l16;
  const short8 qf0 = ld_frag(&qsh[qrow][SWZ(qrow, q4)     * 8]);
  const short8 qf1 = ld_frag(&qsh[qrow][SWZ(qrow, 4 + q4) * 8]);
  const int qi_b = qi0 + qb + q4 * 4;

  // ---- pass 1: rowsums (K dbuf over ksh2[0/1], 1 barrier/iter) ----
  float rsv[4] = {0.f, 0.f, 0.f, 0.f};
  for (int kt = 0; kt < 16; kt++) {
    const int cur = kt & 1;
    if (kt < 15) loadK(kt + 1, kreg);
    #pragma unroll
    for (int nt = 0; nt < 4; nt++) {
      const int krow = nt * 16 + l16;
      floatx4 s = (floatx4){0.f,0.f,0.f,0.f};
      s = __builtin_amdgcn_mfma_f32_16x16x32_bf16(
            qf0, ld_frag(&ksh2[cur][krow][SWZ(krow, q4)     * 8]), s, 0,0,0);
      s = __builtin_amdgcn_mfma_f32_16x16x32_bf16(
            qf1, ld_frag(&ksh2[cur][krow][SWZ(krow, 4 + q4) * 8]), s, 0,0,0);
      int kj = kt * 64 + nt * 16 + l16;
      bool kv = kj < SL;
      const float* mp = Mask + ((size_t)b * SL + qi_b) * SL + kj;
      #pragma unroll
      for (int r = 0; r < 4; r++) {
        int qi = qi_b + r;
        float mval = (kv && qi < SL) ? mp[(size_t)r * SL] : 0.f;
        float sv = fmaxf(s[r] * 0.125f, 0.f) + mval * (-1e9f);
        rsv[r] += kv ? __expf(sv) : 0.f;
      }
    }
    if (kt < 15) writeK(cur ^ 1, kreg);
    __syncthreads();
  }

  // issue pass-2 tile-0 loads early; they fly under the rowsum reduction
  unsigned short vreg[16];
  loadK(0, kreg);
  loadV(0, vreg);

  #pragma unroll
  for (int r = 0; r < 4; r++) {
    #pragma unroll
    for (int off = 1; off < 16; off <<= 1) rsv[r] += __shfl_xor(rsv[r], off, 64);
  }
  float inv[4];
  #pragma unroll
  for (int r = 0; r < 4; r++) inv[r] = 1.f / rsv[r];

  // ---- pass 2: att + PV (K=ksh2[0], V^T=ksh2[1], psh=qsh reuse) ----
  floatx4 oacc[4];
  #pragma unroll
  for (int i = 0; i < 4; i++) oacc[i] = (floatx4){0.f,0.f,0.f,0.f};

  writeK(0, kreg);
  writeV(vreg);
  __syncthreads();

  for (int kt = 0; kt < 16; kt++) {
    if (kt < 15) {                       // issue next-tile loads early
      loadK(kt + 1, kreg);
      loadV(kt + 1, vreg);
    }
    #pragma unroll
    for (int nt = 0; nt < 4; nt++) {
      const int krow = nt * 16 + l16;
      floatx4 s = (floatx4){0.f,0.f,0.f,0.f};
      s = __builtin_amdgcn_mfma_f32_16x16x32_bf16(
            qf0, ld_frag(&ksh2[0][krow][SWZ(krow, q4)     * 8]), s, 0,0,0);
      s = __builtin_amdgcn_mfma_f32_16x16x32_bf16(
            qf1, ld_frag(&ksh2[0][krow][SWZ(krow, 4 + q4) * 8]), s, 0,0,0);
      int kj = kt * 64 + nt * 16 + l16;
      bool kv = kj < SL;
      const float* mp = Mask + ((size_t)b * SL + qi_b) * SL + kj;
      const int pg = nt * 2 + (l16 >> 3), pc = l16 & 7;
      #pragma unroll
      for (int r = 0; r < 4; r++) {
        int qi = qi_b + r;
        bool qv = qi < SL;
        float mval = (kv && qv) ? mp[(size_t)r * SL] : 0.f;
        float sv = fmaxf(s[r] * 0.125f, 0.f) + mval * (-1e9f);
        float p = kv ? __expf(sv) : 0.f;
        float pn = p * inv[r];
        if (kv && qv)
          __builtin_nontemporal_store(pn,
              &Att[(((size_t)(b * NUM_HEADS + h)) * SL + qi) * SL + kj]);
        const int prow = q4 * 4 + r;
        psh[prow][SWZ(prow, pg) * 8 + pc] = f2bf(pn);
      }
    }
    // own-wave P fragments (wave-private rows; no cross-wave barrier needed)
    short8 pa0 = ld_frag(&psh[l16][SWZ(l16, q4)     * 8]);
    short8 pa1 = ld_frag(&psh[l16][SWZ(l16, 4 + q4) * 8]);
    #pragma unroll
    for (int nt2 = 0; nt2 < 4; nt2++) {
      const int vrow = nt2 * 16 + l16;
      oacc[nt2] = __builtin_amdgcn_mfma_f32_16x16x32_bf16(
                    pa0, ld_frag(&ksh2[1][vrow][SWZ(vrow, q4)     * 8]), oacc[nt2], 0,0,0);
      oacc[nt2] = __builtin_amdgcn_mfma_f32_16x16x32_bf16(
                    pa1, ld_frag(&ksh2[1][vrow][SWZ(vrow, 4 + q4) * 8]), oacc[nt2], 0,0,0);
    }
    __syncthreads();                     // all waves done reading K/V of tile kt
    if (kt < 15) {
      writeK(0, kreg);                   // write tile kt+1 (loads landed under compute)
      writeV(vreg);
      __syncthreads();
    }
  }

  #pragma unroll
  for (int nt2 = 0; nt2 < 4; nt2++) {
    #pragma unroll
    for (int r = 0; r < 4; r++) {
      int qi = qi0 + qb + q4 * 4 + r;
      if (qi < SL)
        Out2[((size_t)b * SL + qi) * DM + h * DEPTH + nt2 * 16 + l16] = f2bf(oacc[nt2][r]);
    }
  }
}

extern "C" void kernel_launch(void* const* d_in, const int* in_sizes, int n_in,
                              void* d_out, int out_size, void* d_ws, size_t ws_size,
                              hipStream_t stream) {
  const float* v    = (const float*)d_in[0];
  const float* k    = (const float*)d_in[1];
  const float* q    = (const float*)d_in[2];
  const float* mask = (const float*)d_in[3];
  const float* Wv   = (const float*)d_in[4];
  const float* bv   = (const float*)d_in[5];
  const float* Wd   = (const float*)d_in[6];
  const float* bd   = (const float*)d_in[7];

  float* out = (float*)d_out;                                  // (4,1023,1024) fp32
  float* att = out + (size_t)M_ROWS * DM;                      // (4,16,1023,1023) fp32
  unsigned short* vv   = (unsigned short*)d_ws;                // bf16 (4,1023,1024)
  unsigned short* out2 = vv + (size_t)M_ROWS * DM;             // bf16 (4,1023,1024)

  // scratch inside the att region (dead until attn_kernel writes it):
  unsigned short* WvT = (unsigned short*)att;                  // bf16 [1024][1024] (n-major)
  unsigned short* vbf = WvT + (size_t)DM * DM;                 // bf16 (4,1023,1024)
  // after attn, vv is dead -> reuse its region for WdT:
  unsigned short* WdT = vv;                                    // bf16 [1024][1024]

  const int n8 = (M_ROWS * DM) / 8;                            // 523776

  f32_to_bf16_vec<<<dim3((n8 + 255) / 256), 256, 0, stream>>>(v, vbf, n8);
  transpose_to_bf16<<<dim3(16, 16), 256, 0, stream>>>(Wv, WvT);
  gemm_bt<true><<<dim3(DM/128, (M_ROWS+63)/64), 256, 0, stream>>>(vbf, WvT, bv, (void*)vv, M_ROWS);
  attn_kernel<<<dim3(16, NUM_HEADS, BB), 256, 0, stream>>>(q, k, mask, vv, att, out2);
  transpose_to_bf16<<<dim3(16, 16), 256, 0, stream>>>(Wd, WdT);
  gemm_bt<false><<<dim3(DM/128, (M_ROWS+63)/64), 256, 0, stream>>>(out2, WdT, bd, (void*)out, M_ROWS);
}

// Round 4
// 643.544 us; speedup vs baseline: 1.3142x; 1.3114x over previous
//
#include <hip/hip_runtime.h>
#include <hip/hip_bf16.h>

#define NUM_HEADS 16
#define DM 1024
#define DEPTH 64
#define BB 4
#define SS 1024
#define SL 1023            // S-1
#define M_ROWS (BB*SL)     // 4092

typedef __attribute__((ext_vector_type(8))) short short8;
typedef __attribute__((ext_vector_type(4))) float floatx4;

__device__ inline unsigned short f2bf(float f) {
  __hip_bfloat16 hb = __float2bfloat16(f);
  return *reinterpret_cast<unsigned short*>(&hb);
}
__device__ inline short8 ld_frag(const unsigned short* p) {
  return *reinterpret_cast<const short8*>(p);
}

// XOR granule swizzle: 16B granules within a 128B row; involution.
#define SWZ(row, g) (((g) ^ ((row) & 7)))

// async global->LDS, 16 B per lane (wave-uniform base + lane*16 dest)
#define GLDS(g, l) __builtin_amdgcn_global_load_lds( \
    (const __attribute__((address_space(1))) void*)(g), \
    (__attribute__((address_space(3))) void*)(l), 16, 0, 0)

// ---------------- prep kernels ----------------------------------------------
__global__ __launch_bounds__(256) void f32_to_bf16_vec(
    const float* __restrict__ in, unsigned short* __restrict__ out, int n8)
{
  int i = blockIdx.x * 256 + threadIdx.x;
  if (i >= n8) return;
  const float4 f0 = ((const float4*)in)[(size_t)i * 2];
  const float4 f1 = ((const float4*)in)[(size_t)i * 2 + 1];
  unsigned short t[8];
  t[0]=f2bf(f0.x); t[1]=f2bf(f0.y); t[2]=f2bf(f0.z); t[3]=f2bf(f0.w);
  t[4]=f2bf(f1.x); t[5]=f2bf(f1.y); t[6]=f2bf(f1.z); t[7]=f2bf(f1.w);
  ((uint4*)out)[i] = *(uint4*)t;
}

// W[1024][1024] fp32 -> WT[1024][1024] bf16 with WT[n][k] = W[k][n]
__global__ __launch_bounds__(256) void transpose_to_bf16(
    const float* __restrict__ W, unsigned short* __restrict__ WT)
{
  __shared__ unsigned short tile[64][72];
  const int tid = threadIdx.x;
  const int k0 = blockIdx.y * 64, n0 = blockIdx.x * 64;
  {
    const int kl = tid >> 2, nc = (tid & 3) * 16;
    const float* src = W + (size_t)(k0 + kl) * DM + n0 + nc;
    #pragma unroll
    for (int j = 0; j < 16; j += 4) {
      float4 f = *(const float4*)(src + j);
      tile[nc + j + 0][kl] = f2bf(f.x);
      tile[nc + j + 1][kl] = f2bf(f.y);
      tile[nc + j + 2][kl] = f2bf(f.z);
      tile[nc + j + 3][kl] = f2bf(f.w);
    }
  }
  __syncthreads();
  {
    const int nl = tid >> 2, kc = (tid & 3) * 16;
    unsigned short tmp[16];
    #pragma unroll
    for (int j = 0; j < 16; j++) tmp[j] = tile[nl][kc + j];
    unsigned short* dst = WT + (size_t)(n0 + nl) * DM + k0 + kc;
    *(uint4*)&dst[0] = *(uint4*)&tmp[0];
    *(uint4*)&dst[8] = *(uint4*)&tmp[8];
  }
}

// ---------------- GEMM: C[M x 1024] = A * BT^T + bias -----------------------
// A bf16 [M][K], BT bf16 [N][K]. BM=64 BN=128 BK=64, 4 waves (2x2), wave 32x64.
// 3-stage pipeline, counted vmcnt (never drained to 0 in the loop), raw
// s_barrier (no implicit vmcnt drain). Per iter:
//   vmcnt(12) ; bar ; ds_read x12 ; lgkmcnt(0) ; bar ; GLDS stage t+3 ; 16 MFMA
// Race-free: all waves pass barrier-2 only after completing their ds_reads,
// so re-staging into the just-read buffer cannot overwrite live data.
template <bool OUT_BF16>
__global__ __launch_bounds__(256) void gemm_bt(
    const unsigned short* __restrict__ A,   // [M][DM] bf16
    const unsigned short* __restrict__ BT,  // [DM][DM] bf16 (n-major)
    const float* __restrict__ bias,
    void* __restrict__ Cv, int M)
{
  constexpr int BM = 64, BN = 128, BK = 64;
  __shared__ __align__(16) unsigned short As[3][BM * BK];   // 3 x 8 KB
  __shared__ __align__(16) unsigned short Bs[3][BN * BK];   // 3 x 16 KB  (72 KB total)

  const int tid = threadIdx.x;
  const int w = tid >> 6, lane = tid & 63, q4 = lane >> 4, l16 = lane & 15;
  const int wm = w >> 1, wn = w & 1;
  const int rb = blockIdx.y * BM;
  const int cb = blockIdx.x * BN;

  // wave-uniform LDS offset (u16 index): wave w covers bytes [w*1024, w*1024+1024)
  const int wbase = __builtin_amdgcn_readfirstlane(w * 512);

  // staging: each 4KB chunk = 32 rows x 128B; thread t -> row t>>3, phys granule t&7
  const int srow = tid >> 3;                   // 0..31
  const int lg   = (tid & 7) ^ (srow & 7);     // logical granule (inverse swizzle)
  int ar0 = rb + srow;       if (ar0 >= M) ar0 = M - 1;
  int ar1 = rb + 32 + srow;  if (ar1 >= M) ar1 = M - 1;
  const unsigned short* a_src0 = A + (size_t)ar0 * DM + lg * 8;
  const unsigned short* a_src1 = A + (size_t)ar1 * DM + lg * 8;
  const unsigned short* b_src0 = BT + (size_t)(cb      + srow) * DM + lg * 8;
  const unsigned short* b_src1 = BT + (size_t)(cb + 32 + srow) * DM + lg * 8;
  const unsigned short* b_src2 = BT + (size_t)(cb + 64 + srow) * DM + lg * 8;
  const unsigned short* b_src3 = BT + (size_t)(cb + 96 + srow) * DM + lg * 8;

  auto stage = [&](int t, unsigned short* Ab, unsigned short* Bb) {
    const int kn = t * BK;
    GLDS(a_src0 + kn, Ab + wbase);
    GLDS(a_src1 + kn, Ab + 2048 + wbase);
    GLDS(b_src0 + kn, Bb + wbase);
    GLDS(b_src1 + kn, Bb + 2048 + wbase);
    GLDS(b_src2 + kn, Bb + 4096 + wbase);
    GLDS(b_src3 + kn, Bb + 6144 + wbase);
  };

  // fragment read offsets (u16 index), swizzled
  int aoff[2][2], boff[4][2];
  #pragma unroll
  for (int i = 0; i < 2; i++)
    #pragma unroll
    for (int hf = 0; hf < 2; hf++) {
      int r = wm * 32 + i * 16 + l16;
      aoff[i][hf] = r * BK + SWZ(r, q4 + 4 * hf) * 8;
    }
  #pragma unroll
  for (int j = 0; j < 4; j++)
    #pragma unroll
    for (int hf = 0; hf < 2; hf++) {
      int r = wn * 64 + j * 16 + l16;
      boff[j][hf] = r * BK + SWZ(r, q4 + 4 * hf) * 8;
    }

  floatx4 acc[2][4];
  #pragma unroll
  for (int i = 0; i < 2; i++)
    #pragma unroll
    for (int j = 0; j < 4; j++) acc[i][j] = (floatx4){0.f,0.f,0.f,0.f};

  // prologue: stage tiles 0,1,2 (18 loads in flight)
  stage(0, As[0], Bs[0]);
  stage(1, As[1], Bs[1]);
  stage(2, As[2], Bs[2]);

  int cur = 0;
  constexpr int NT = DM / BK;   // 16
  for (int t = 0; t < NT; ++t) {
    // wait for stage t only (leave later stages in flight), then barrier
    if (t < NT - 2)       asm volatile("s_waitcnt vmcnt(12)" ::: "memory");
    else if (t == NT - 2) asm volatile("s_waitcnt vmcnt(6)"  ::: "memory");
    else                  asm volatile("s_waitcnt vmcnt(0)"  ::: "memory");
    __builtin_amdgcn_sched_barrier(0);
    __builtin_amdgcn_s_barrier();
    __builtin_amdgcn_sched_barrier(0);

    unsigned short* Ab = As[cur];
    unsigned short* Bb = Bs[cur];
    short8 af[2][2], bfr[4][2];
    #pragma unroll
    for (int hf = 0; hf < 2; hf++) {
      af[0][hf] = ld_frag(Ab + aoff[0][hf]);
      af[1][hf] = ld_frag(Ab + aoff[1][hf]);
      bfr[0][hf] = ld_frag(Bb + boff[0][hf]);
      bfr[1][hf] = ld_frag(Bb + boff[1][hf]);
      bfr[2][hf] = ld_frag(Bb + boff[2][hf]);
      bfr[3][hf] = ld_frag(Bb + boff[3][hf]);
    }
    // all reads complete before any wave may re-stage this buffer
    asm volatile("s_waitcnt lgkmcnt(0)" ::: "memory");
    __builtin_amdgcn_sched_barrier(0);
    __builtin_amdgcn_s_barrier();
    __builtin_amdgcn_sched_barrier(0);

    if (t + 3 < NT) stage(t + 3, Ab, Bb);   // into just-freed buffer

    #pragma unroll
    for (int hf = 0; hf < 2; hf++) {
      acc[0][0] = __builtin_amdgcn_mfma_f32_16x16x32_bf16(af[0][hf], bfr[0][hf], acc[0][0], 0,0,0);
      acc[0][1] = __builtin_amdgcn_mfma_f32_16x16x32_bf16(af[0][hf], bfr[1][hf], acc[0][1], 0,0,0);
      acc[0][2] = __builtin_amdgcn_mfma_f32_16x16x32_bf16(af[0][hf], bfr[2][hf], acc[0][2], 0,0,0);
      acc[0][3] = __builtin_amdgcn_mfma_f32_16x16x32_bf16(af[0][hf], bfr[3][hf], acc[0][3], 0,0,0);
      acc[1][0] = __builtin_amdgcn_mfma_f32_16x16x32_bf16(af[1][hf], bfr[0][hf], acc[1][0], 0,0,0);
      acc[1][1] = __builtin_amdgcn_mfma_f32_16x16x32_bf16(af[1][hf], bfr[1][hf], acc[1][1], 0,0,0);
      acc[1][2] = __builtin_amdgcn_mfma_f32_16x16x32_bf16(af[1][hf], bfr[2][hf], acc[1][2], 0,0,0);
      acc[1][3] = __builtin_amdgcn_mfma_f32_16x16x32_bf16(af[1][hf], bfr[3][hf], acc[1][3], 0,0,0);
    }
    cur = (cur == 2) ? 0 : cur + 1;
  }

  // epilogue
  #pragma unroll
  for (int j = 0; j < 4; j++) {
    int col = cb + wn * 64 + j * 16 + l16;
    float bb = bias[col];
    #pragma unroll
    for (int i = 0; i < 2; i++) {
      #pragma unroll
      for (int r = 0; r < 4; r++) {
        int m = rb + wm * 32 + i * 16 + q4 * 4 + r;
        if (m < M) {
          float val = acc[i][j][r] + bb;
          if (OUT_BF16) ((unsigned short*)Cv)[(size_t)m * DM + col] = f2bf(val);
          else __builtin_nontemporal_store(val, &((float*)Cv)[(size_t)m * DM + col]);
        }
      }
    }
  }
}

// ---------------- Attention (proven R0 structure; blockIdx.x = head) --------
// grid (16 heads, 16 q-tiles, 4 batch); block 256 = 4 waves, wave owns 16 q rows.
// blockIdx.x = h so all q-tile blocks of one (b,h) land on one XCD (linear%8
// heuristic) -> K/V panel cached once per XCD L2.
__global__ __launch_bounds__(256) void attn_kernel(
    const float* __restrict__ Q, const float* __restrict__ Kg,
    const float* __restrict__ Mask, const unsigned short* __restrict__ VV,
    float* __restrict__ Att, unsigned short* __restrict__ Out2)
{
  const int h = blockIdx.x, qt = blockIdx.y, b = blockIdx.z;
  const int tid = threadIdx.x;
  const int w = tid >> 6, lane = tid & 63, q4 = lane >> 4, l16 = lane & 15;
  const int qi0 = qt * 64;
  const int qb = w * 16;

  __shared__ unsigned short qsh[64][72];     // [q][d]   (bf16, pad: 144 B rows)
  __shared__ unsigned short ksh[64][72];     // [key][d]
  __shared__ unsigned short vshT[64][72];    // [d][key] (transposed)
  __shared__ unsigned short psh[4][16][72];  // per-wave P [q][key]

  // stage Q tile (query row qi reads q[b][qi+1][h*64 + d])
  {
    int qr = tid >> 2, d0 = (tid & 3) * 16;
    int qi = qi0 + qr;
    unsigned short tmp[16];
    if (qi < SL) {
      const float* src = Q + ((size_t)b * SS + qi + 1) * DM + h * DEPTH + d0;
      #pragma unroll
      for (int j = 0; j < 16; j += 4) {
        float4 f = *(const float4*)(src + j);
        tmp[j+0]=f2bf(f.x); tmp[j+1]=f2bf(f.y); tmp[j+2]=f2bf(f.z); tmp[j+3]=f2bf(f.w);
      }
    } else {
      #pragma unroll
      for (int j = 0; j < 16; j++) tmp[j] = 0;
    }
    *(uint4*)&qsh[qr][d0]     = *(uint4*)&tmp[0];
    *(uint4*)&qsh[qr][d0 + 8] = *(uint4*)&tmp[8];
  }

  auto stageK = [&](int kt) {
    int kr = tid >> 2, d0 = (tid & 3) * 16;
    int kj = kt * 64 + kr;
    unsigned short tmp[16];
    if (kj < SL) {
      const float* src = Kg + ((size_t)b * SS + kj) * DM + h * DEPTH + d0;
      #pragma unroll
      for (int j = 0; j < 16; j += 4) {
        float4 f = *(const float4*)(src + j);
        tmp[j+0]=f2bf(f.x); tmp[j+1]=f2bf(f.y); tmp[j+2]=f2bf(f.z); tmp[j+3]=f2bf(f.w);
      }
    } else {
      #pragma unroll
      for (int j = 0; j < 16; j++) tmp[j] = 0;
    }
    *(uint4*)&ksh[kr][d0]     = *(uint4*)&tmp[0];
    *(uint4*)&ksh[kr][d0 + 8] = *(uint4*)&tmp[8];
  };

  auto stageV = [&](int kt) {   // vshT[d][key_local], bf16 source in ws
    int d = tid & 63, k16 = (tid >> 6) * 16;
    unsigned short tmp[16];
    #pragma unroll
    for (int j = 0; j < 16; j++) {
      int kj = kt * 64 + k16 + j;
      tmp[j] = (kj < SL) ? VV[((size_t)b * SL + kj) * DM + h * DEPTH + d] : (unsigned short)0;
    }
    *(uint4*)&vshT[d][k16]     = *(uint4*)&tmp[0];
    *(uint4*)&vshT[d][k16 + 8] = *(uint4*)&tmp[8];
  };

  __syncthreads();

  // ---- pass 1: rowsums ----
  float rsv[4] = {0.f, 0.f, 0.f, 0.f};
  for (int kt = 0; kt < 16; kt++) {
    __syncthreads();
    stageK(kt);
    __syncthreads();
    #pragma unroll
    for (int nt = 0; nt < 4; nt++) {
      floatx4 s = (floatx4){0.f,0.f,0.f,0.f};
      s = __builtin_amdgcn_mfma_f32_16x16x32_bf16(
            ld_frag(&qsh[qb + l16][q4*8]), ld_frag(&ksh[nt*16 + l16][q4*8]), s, 0,0,0);
      s = __builtin_amdgcn_mfma_f32_16x16x32_bf16(
            ld_frag(&qsh[qb + l16][32 + q4*8]), ld_frag(&ksh[nt*16 + l16][32 + q4*8]), s, 0,0,0);
      int kj = kt * 64 + nt * 16 + l16;
      bool kv = kj < SL;
      int qi_b = qi0 + qb + q4 * 4;
      const float* mp = Mask + ((size_t)b * SL + qi_b) * SL + kj;
      #pragma unroll
      for (int r = 0; r < 4; r++) {
        int qi = qi_b + r;
        float mval = (kv && qi < SL) ? mp[(size_t)r * SL] : 0.f;
        float sv = fmaxf(s[r] * 0.125f, 0.f) + mval * (-1e9f);
        float p = kv ? __expf(sv) : 0.f;
        rsv[r] += p;
      }
    }
  }
  #pragma unroll
  for (int r = 0; r < 4; r++) {
    #pragma unroll
    for (int off = 1; off < 16; off <<= 1) rsv[r] += __shfl_xor(rsv[r], off, 64);
  }
  float inv[4];
  #pragma unroll
  for (int r = 0; r < 4; r++) inv[r] = 1.f / rsv[r];

  // ---- pass 2: att + PV ----
  floatx4 oacc[4];
  #pragma unroll
  for (int i = 0; i < 4; i++) oacc[i] = (floatx4){0.f,0.f,0.f,0.f};

  for (int kt = 0; kt < 16; kt++) {
    __syncthreads();
    stageK(kt);
    stageV(kt);
    __syncthreads();
    #pragma unroll
    for (int nt = 0; nt < 4; nt++) {
      floatx4 s = (floatx4){0.f,0.f,0.f,0.f};
      s = __builtin_amdgcn_mfma_f32_16x16x32_bf16(
            ld_frag(&qsh[qb + l16][q4*8]), ld_frag(&ksh[nt*16 + l16][q4*8]), s, 0,0,0);
      s = __builtin_amdgcn_mfma_f32_16x16x32_bf16(
            ld_frag(&qsh[qb + l16][32 + q4*8]), ld_frag(&ksh[nt*16 + l16][32 + q4*8]), s, 0,0,0);
      int kj = kt * 64 + nt * 16 + l16;
      bool kv = kj < SL;
      int qi_b = qi0 + qb + q4 * 4;
      const float* mp = Mask + ((size_t)b * SL + qi_b) * SL + kj;
      #pragma unroll
      for (int r = 0; r < 4; r++) {
        int qi = qi_b + r;
        bool qv = qi < SL;
        float mval = (kv && qv) ? mp[(size_t)r * SL] : 0.f;
        float sv = fmaxf(s[r] * 0.125f, 0.f) + mval * (-1e9f);
        float p = kv ? __expf(sv) : 0.f;
        float pn = p * inv[r];
        if (kv && qv)
          Att[(((size_t)(b * NUM_HEADS + h)) * SL + qi) * SL + kj] = pn;
        psh[w][q4 * 4 + r][nt * 16 + l16] = f2bf(pn);
      }
    }
    // PV: oacc(16q x 64d) += P(16q x 64k) @ V(64k x 64d)
    short8 pa0 = ld_frag(&psh[w][l16][q4 * 8]);
    short8 pa1 = ld_frag(&psh[w][l16][32 + q4 * 8]);
    #pragma unroll
    for (int nt2 = 0; nt2 < 4; nt2++) {
      oacc[nt2] = __builtin_amdgcn_mfma_f32_16x16x32_bf16(
                    pa0, ld_frag(&vshT[nt2*16 + l16][q4*8]), oacc[nt2], 0,0,0);
      oacc[nt2] = __builtin_amdgcn_mfma_f32_16x16x32_bf16(
                    pa1, ld_frag(&vshT[nt2*16 + l16][32 + q4*8]), oacc[nt2], 0,0,0);
    }
  }

  #pragma unroll
  for (int nt2 = 0; nt2 < 4; nt2++) {
    #pragma unroll
    for (int r = 0; r < 4; r++) {
      int qi = qi0 + qb + q4 * 4 + r;
      if (qi < SL)
        Out2[((size_t)b * SL + qi) * DM + h * DEPTH + nt2 * 16 + l16] = f2bf(oacc[nt2][r]);
    }
  }
}

extern "C" void kernel_launch(void* const* d_in, const int* in_sizes, int n_in,
                              void* d_out, int out_size, void* d_ws, size_t ws_size,
                              hipStream_t stream) {
  const float* v    = (const float*)d_in[0];
  const float* k    = (const float*)d_in[1];
  const float* q    = (const float*)d_in[2];
  const float* mask = (const float*)d_in[3];
  const float* Wv   = (const float*)d_in[4];
  const float* bv   = (const float*)d_in[5];
  const float* Wd   = (const float*)d_in[6];
  const float* bd   = (const float*)d_in[7];

  float* out = (float*)d_out;                                  // (4,1023,1024) fp32
  float* att = out + (size_t)M_ROWS * DM;                      // (4,16,1023,1023) fp32
  unsigned short* vv   = (unsigned short*)d_ws;                // bf16 (4,1023,1024)
  unsigned short* out2 = vv + (size_t)M_ROWS * DM;             // bf16 (4,1023,1024)

  // scratch inside the att region (dead until attn_kernel writes it):
  unsigned short* WvT = (unsigned short*)att;                  // bf16 [1024][1024] (n-major)
  unsigned short* vbf = WvT + (size_t)DM * DM;                 // bf16 (4,1023,1024)
  // after attn, vv is dead -> reuse its region for WdT:
  unsigned short* WdT = vv;                                    // bf16 [1024][1024]

  const int n8 = (M_ROWS * DM) / 8;                            // 523776

  f32_to_bf16_vec<<<dim3((n8 + 255) / 256), 256, 0, stream>>>(v, vbf, n8);
  transpose_to_bf16<<<dim3(16, 16), 256, 0, stream>>>(Wv, WvT);
  gemm_bt<true><<<dim3(DM/128, (M_ROWS+63)/64), 256, 0, stream>>>(vbf, WvT, bv, (void*)vv, M_ROWS);
  attn_kernel<<<dim3(NUM_HEADS, 16, BB), 256, 0, stream>>>(q, k, mask, vv, att, out2);
  transpose_to_bf16<<<dim3(16, 16), 256, 0, stream>>>(Wd, WdT);
  gemm_bt<false><<<dim3(DM/128, (M_ROWS+63)/64), 256, 0, stream>>>(out2, WdT, bd, (void*)out, M_ROWS);
}